// Round 1
// baseline (1781.129 us; speedup 1.0000x reference)
//
#include <hip/hip_runtime.h>
#include <math.h>

#define NMAT 50000
#define MPB 8                    // matrices per block: 256 thr = 4 waves = 8 half-waves
#define NBLK (NMAT / MPB)        // 6250

__device__ __forceinline__ float frcp(float x)  { return __builtin_amdgcn_rcpf(x); }
__device__ __forceinline__ float frsq(float x)  { return __builtin_amdgcn_rsqf(x); }
__device__ __forceinline__ float fsqrt_(float x){ return __builtin_amdgcn_sqrtf(x); }

// sum across the 32-lane half-wave (all lanes get the result)
__device__ __forceinline__ float red32(float x) {
  x += __shfl_xor(x, 1, 32);
  x += __shfl_xor(x, 2, 32);
  x += __shfl_xor(x, 4, 32);
  x += __shfl_xor(x, 8, 32);
  x += __shfl_xor(x, 16, 32);
  return x;
}

__global__ __launch_bounds__(256) void riem_batch(const float* __restrict__ X,
                                                  const float* __restrict__ Y,
                                                  float* __restrict__ partial) {
  const int tid = threadIdx.x;
  const int c   = tid & 31;        // column owned by this lane
  const int hw  = tid >> 5;        // half-wave id within block (0..7)
  const long mat = (long)blockIdx.x * MPB + hw;
  const float* Yp = Y + mat * 1024;
  const float* Xp = X + mat * 1024;

  __shared__ float tbuf[MPB][1056];   // 32x33 padded transpose buffer per matrix
  __shared__ float psum[MPB];

  // ---- load Y columns: lane c holds Y[:,c] ----
  float m[32];
#pragma unroll
  for (int i = 0; i < 32; ++i) m[i] = Yp[i * 32 + c];

  // ---- square-root-free symmetric elimination: Y = Lt * D * Lt^T ----
  // lane c ends holding pivot column c; dc = D[c], rc = 1/D[c]
  float dc = 1.0f, rc = 1.0f;
#pragma unroll
  for (int j = 0; j < 32; ++j) {
    float piv  = __shfl(m[j], j, 32);      // D[j], wave-uniform (per half)
    float rinv = frcp(piv);
    if (c == j) { dc = piv; rc = rinv; }
    float t = (c > j) ? m[j] * rinv : 0.0f;   // frozen columns (c<=j) untouched
#pragma unroll
    for (int i = j + 1; i < 32; ++i)
      m[i] = fmaf(-__shfl(m[i], j, 32), t, m[i]);
  }
  float dsv = frsq(dc);                     // D[c]^{-1/2}
#pragma unroll
  for (int i = 0; i < 32; ++i) m[i] *= rc;  // unit-lower Lt columns (above-diag junk unused)

  // ---- load X columns, forward solve W = Lt^{-1} X ----
  float x[32];
#pragma unroll
  for (int i = 0; i < 32; ++i) x[i] = Xp[i * 32 + c];
#pragma unroll
  for (int k = 0; k < 31; ++k) {
#pragma unroll
    for (int i = k + 1; i < 32; ++i)
      x[i] = fmaf(-__shfl(m[i], k, 32), x[k], x[i]);   // Lt[i][k] from lane k
  }

  // ---- transpose W within the half-wave via padded LDS ----
  float* tb = tbuf[hw];
#pragma unroll
  for (int i = 0; i < 32; ++i) tb[c * 33 + i] = x[i];
  __syncthreads();
#pragma unroll
  for (int i = 0; i < 32; ++i) x[i] = tb[i * 33 + c];

  // ---- second solve: V = Lt^{-1} W^T (V symmetric), then A = D^{-1/2} V D^{-1/2} ----
#pragma unroll
  for (int k = 0; k < 31; ++k) {
#pragma unroll
    for (int i = k + 1; i < 32; ++i)
      x[i] = fmaf(-__shfl(m[i], k, 32), x[k], x[i]);
  }
#pragma unroll
  for (int i = 0; i < 32; ++i) x[i] = x[i] * __shfl(dsv, i, 32) * dsv;

  // ---- Householder tridiagonalization of A (columns in x[], rank-2 updates) ----
  float e2[31];
  float e2max = 0.0f;
#pragma unroll
  for (int k = 0; k < 30; ++k) {
    float colv  = x[k];                              // A[c][k]
    float sq    = (c > k) ? colv * colv : 0.0f;
    float sigma = red32(sq);                         // ||A[k+1:,k]||^2 = alpha^2
    float akk1  = __shfl(x[k], k + 1, 32);           // A[k+1][k]
    e2[k] = sigma;                                   // e_k^2 = sigma exactly
    e2max = fmaxf(e2max, sigma);
    float nrm   = fsqrt_(sigma);
    float alpha = (akk1 >= 0.0f) ? -nrm : nrm;
    float denom = fmaf(-alpha, akk1, sigma);         // sigma + |akk1|*nrm = vTv/2
    float tau   = frcp(fmaxf(denom, 1e-35f));        // 2/vTv; sigma==0 -> v==0 no-op
    float v     = (c == k + 1) ? (akk1 - alpha) : ((c > k + 1) ? colv : 0.0f);
    float acc = 0.0f;
#pragma unroll
    for (int j = k + 1; j < 32; ++j) acc = fmaf(x[j], __shfl(v, j, 32), acc);
    float p = tau * acc;                             // p = tau * A v (per row)
    float K = 0.5f * tau * red32(v * p);             // (tau/2) vTp
    float q = fmaf(-K, v, p);
#pragma unroll
    for (int j = k + 1; j < 32; ++j) {               // A -= v q^T + q v^T
      float vb = __shfl(v, j, 32);
      float qb = __shfl(q, j, 32);
      x[j] = fmaf(-v, qb, fmaf(-q, vb, x[j]));
    }
  }
  {
    float el = __shfl(x[30], 31, 32);                // trailing subdiagonal
    e2[30] = el * el;
    e2max  = fmaxf(e2max, e2[30]);
  }

  // ---- extract tridiagonal diag, Gershgorin bounds ----
  float dg[32];
#pragma unroll
  for (int i = 0; i < 32; ++i) dg[i] = __shfl(x[i], i, 32);
  float dmin = dg[0], dmax = dg[0];
#pragma unroll
  for (int i = 1; i < 32; ++i) { dmin = fminf(dmin, dg[i]); dmax = fmaxf(dmax, dg[i]); }
  float er = 2.0f * fsqrt_(e2max);
  float lo = fmaxf(dmin - er, 1e-3f);   // A is SPD with lambda_min >~ 0.15 by construction
  float hi = dmax + er;

  // ---- bisection with Sturm counts: lane c converges to eigenvalue #c ----
  for (int it = 0; it < 18; ++it) {
    float mid = 0.5f * (lo + hi);
    float qq  = dg[0] - mid;
    qq = (fabsf(qq) < 1e-30f) ? -1e-30f : qq;
    int cnt = (qq < 0.0f) ? 1 : 0;
#pragma unroll
    for (int i = 1; i < 32; ++i) {
      qq = (dg[i] - mid) - e2[i - 1] * frcp(qq);
      qq = (fabsf(qq) < 1e-30f) ? -1e-30f : qq;      // pivmin clamp: no inf*0
      cnt += (qq < 0.0f) ? 1 : 0;
    }
    bool le = (cnt <= c);
    lo = le ? mid : lo;
    hi = le ? hi : mid;
  }

  float lam = 0.5f * (lo + hi);
  float lg  = __logf(lam);
  float s   = red32(lg * lg);
  float db  = fsqrt_(s);                 // d(x_b, y_b)

  if (c == 0) psum[hw] = db;
  __syncthreads();
  if (tid == 0) {
    float t = 0.0f;
#pragma unroll
    for (int i = 0; i < MPB; ++i) t += psum[i];
    partial[blockIdx.x] = t;
  }
}

__global__ __launch_bounds__(256) void riem_finish(const float* __restrict__ partial,
                                                   float* __restrict__ out) {
  float acc = 0.0f;
  for (int i = threadIdx.x; i < NBLK; i += 256) acc += partial[i];
  acc += __shfl_xor(acc, 1);
  acc += __shfl_xor(acc, 2);
  acc += __shfl_xor(acc, 4);
  acc += __shfl_xor(acc, 8);
  acc += __shfl_xor(acc, 16);
  acc += __shfl_xor(acc, 32);
  __shared__ float ps[4];
  if ((threadIdx.x & 63) == 0) ps[threadIdx.x >> 6] = acc;
  __syncthreads();
  if (threadIdx.x == 0)
    out[0] = (ps[0] + ps[1] + ps[2] + ps[3]) * (1.0f / (float)NMAT);
}

extern "C" void kernel_launch(void* const* d_in, const int* in_sizes, int n_in,
                              void* d_out, int out_size, void* d_ws, size_t ws_size,
                              hipStream_t stream) {
  const float* x = (const float*)d_in[0];
  const float* y = (const float*)d_in[1];
  float* out  = (float*)d_out;
  float* part = (float*)d_ws;   // NBLK floats = 25 KB
  riem_batch<<<NBLK, 256, 0, stream>>>(x, y, part);
  riem_finish<<<1, 256, 0, stream>>>(part, out);
}